// Round 16
// baseline (208.555 us; speedup 1.0000x reference)
//
#include <hip/hip_runtime.h>
#include <math.h>

// CapsNet fused forward, v19: v18 with prim A-operands staged through LDS via
// global_load_lds (register-free prefetch FIFO).
// v18 finding: regalloc sinks a register FIFO regardless of VGPR budget
// (VGPR=64 at both (256,4) and (256,3)). prim's ~50us marginal is serialized
// global A-load latency. Fix: 4 LDS tap-buffers per wave (2KB each); issue
// tap k+3 with __builtin_amdgcn_global_load_lds (no VGPR cost), counted
// s_waitcnt vmcnt(6) (taps k+1..k+3 stay in flight, never drain to 0),
// then ds_read_b128 the A fragments (64 lanes cover distinct 16B blocks of
// the 2KB buffer = volume-bound, conflict-free). Overwrite target buffer was
// consumed one full iteration earlier -> no read/overwrite hazard.
// LDS 69.8KB -> 2 blocks/CU (v5==v7 proved >=2 blocks/CU is sufficient TLP).
// Everything outside the prim phase is byte-identical to v18.

typedef __attribute__((ext_vector_type(8))) short bf16x8;
typedef __attribute__((ext_vector_type(4))) float f32x4;

__device__ inline unsigned short f2bf(float f) {
    union { float f; unsigned u; } v; v.f = f;
    unsigned r = v.u + 0x7fff + ((v.u >> 16) & 1);   // RNE
    return (unsigned short)(r >> 16);
}

__device__ inline void gload16(const unsigned short* g, unsigned short* l) {
    __builtin_amdgcn_global_load_lds(
        (const __attribute__((address_space(1))) void*)g,
        (__attribute__((address_space(3))) void*)l,
        16, 0, 0);
}

#define C1TN 16008   // u16 per c1t slice (400*40 + 8 skew pad)

// ---------------- pre kernel ----------------
__global__ void caps_pre(const float* __restrict__ conv1_w,
                         const float* __restrict__ prim_w,
                         const float* __restrict__ dig_Wb,
                         const float* __restrict__ out_w,
                         float* __restrict__ S,              // [B*16]
                         float* __restrict__ colsum,         // [16]
                         float* __restrict__ OW,             // [160]
                         unsigned short* __restrict__ c1wp2, // [256*96]
                         unsigned short* __restrict__ pw2,   // [85*1024]
                         unsigned int* __restrict__ cnt,     // [B]
                         int B)
{
    const int t = threadIdx.x;
    const int bx = blockIdx.x;

    if (bx < 32) {
        // pw2 build for o = bx: coalesced read + LDS transpose + coalesced write
        __shared__ float lw[2592];                  // [32 caps][81 taps]
        const float* src = prim_w + bx * 32 * 81;
        for (int j = t; j < 2592; j += 256) lw[j] = src[j];
        __syncthreads();
        unsigned short* dst = pw2 + bx * 32;
        for (int f = t; f < 2720; f += 256) {       // 85 taps * 32 slots
            const int tap = f >> 5, s = f & 31;
            const int ci = (s >> 1) + ((s & 1) << 4);   // interleaved caps slot
            const unsigned short v =
                (tap < 81) ? f2bf(lw[ci * 81 + tap]) : (unsigned short)0;
            dst[tap * 1024 + s] = v;
        }
        return;
    }
    if (bx < 128) {                                 // c1wp2, K-permuted
        const int tid = (bx - 32) * 256 + t;        // [0, 24576)
        const int c = tid / 96, kn = tid % 96;
        unsigned short v = 0;
        if (kn < 72) {
            const int p = kn >> 1, lo = kn & 1, ky = p >> 2, kx = 2 * (p & 3) + lo;
            v = f2bf(conv1_w[c * 81 + 9 * ky + kx]);
        } else if (kn < 81) {
            v = f2bf(conv1_w[c * 81 + 9 * (kn - 72) + 8]);
        }
        c1wp2[tid] = v;
        return;
    }
    if (bx == 128) {                                // colsum + OW
        __shared__ float cs[16];
        if (t < 16) cs[t] = 0.f;
        __syncthreads();
        {
            const int k = t & 15, g = t >> 4;
            float s = 0.f;
            for (int j = 0; j < 72; ++j) s += dig_Wb[(g * 72 + j) * 16 + k];
            atomicAdd(&cs[k], s);
        }
        __syncthreads();
        if (t < 16) colsum[t] = cs[t];
        if (t >= 64 && t < 224) {
            const int idx = t - 64, o = idx >> 4, k = idx & 15;
            float s = 0.f;
            for (int i = 0; i < 10; ++i) s += out_w[(o * 10 + i) * 16 + k];
            OW[idx] = s;
        }
        return;
    }
    const int idx = (bx - 129) * 256 + t;           // S / cnt zero
    if (idx < B * 16) S[idx] = 0.f;
    else if (idx < B * 17) cnt[idx - B * 16] = 0u;
}

// ---------------- main kernel (epilogue fused, fence-free) ----------------
__global__ __launch_bounds__(256, 2) void caps_main(
    const float* __restrict__ x,
    const float* __restrict__ conv1_b,
    const float* __restrict__ prim_b,
    const float* __restrict__ dig_W,
    const unsigned short* __restrict__ c1wp2,
    const unsigned short* __restrict__ pw2,
    float* __restrict__ S,
    const float* __restrict__ colsum,
    const float* __restrict__ OW,
    const float* __restrict__ out_b,
    unsigned int* __restrict__ cnt,
    float* __restrict__ out)
{
    __shared__ __align__(16) unsigned short c1t[C1TN];      // 32 KB (1 d-slice)
    __shared__ __align__(16) unsigned short abuf[4][4][1024]; // 32 KB A-FIFO
    __shared__ __align__(16) unsigned imgp[1120];           // 28x40-dw bf16-pair grid
    __shared__ unsigned short offT[64];                     // byte offsets into imgp
    __shared__ float pbs[32];
    __shared__ float sacc[64];                              // per-wave S partials

    const int b = blockIdx.x >> 3, d = blockIdx.x & 7;
    const int t = threadIdx.x;
    const int wave = t >> 6, lane = t & 63, quad = lane >> 4, l16 = lane & 15;

    // ---- prim tap partition: contiguous per wave (w3: 18 real taps) ----
    const int base = wave * 21;                 // 0,21,42,63
    const int ntap = (wave == 3) ? 18 : 21;

    // ---- prologue: issue taps 0-2 into LDS A-FIFO (fire-and-forget) ----
#pragma unroll
    for (int p = 0; p < 3; ++p) {
        const unsigned short* g = pw2 + (base + p) * 1024 + lane * 8;
        unsigned short* l = &abuf[wave][p][0];
        gload16(g, l);
        gload16(g + 512, l + 512);
    }
    // ---- hoisted conv1 weight frags + biases (v15 win) ----
    bf16x8 Bw0[3], Bw1[3];
#pragma unroll
    for (int ks = 0; ks < 3; ++ks) {
        Bw0[ks] = *(const bf16x8*)&c1wp2[(l16 * 8 + d) * 96 + ks * 32 + quad * 8];
        Bw1[ks] = *(const bf16x8*)&c1wp2[((16 + l16) * 8 + d) * 96 + ks * 32 + quad * 8];
    }
    const float cb0 = conv1_b[l16 * 8 + d];
    const float cb1 = conv1_b[(16 + l16) * 8 + d];
    __builtin_amdgcn_sched_barrier(0);          // loads may not sink past here

    // ---- imgp staging, vectorized, 28x40-dw grid ----
    const float* xb = x + b * 784;
    if (t < 196) {
        const float4 f4 = *(const float4*)(xb + 4 * t);
        const float nxt = (t < 195) ? xb[4 * t + 4] : 0.f;
        const float e[5] = {f4.x, f4.y, f4.z, f4.w, nxt};
#pragma unroll
        for (int r = 0; r < 4; ++r) {
            const int j = 4 * t + r;
            const int y = (int)(((unsigned)j * 37450u) >> 20);   // j/28
            const int xc = j - 28 * y;
            const float cnext = (xc < 27) ? e[r + 1] : 0.f;
            imgp[y * 40 + xc] = (unsigned)f2bf(e[r]) | ((unsigned)f2bf(cnext) << 16);
        }
    }
    // zero-fill cols 28..39 (includes the uniform dead-tap dword at index 28)
    for (int j = t; j < 1120; j += 256) {
        const int y = (int)(((unsigned)j * 1639u) >> 16);        // j/40
        if (j - 40 * y >= 28) imgp[j] = 0u;
    }
    // ---- tap-offset tables (byte offsets, x4), stride-40 grid ----
    if (t < 64) {
        int v;
        if (t < 32) {
            const int ky = t >> 2, kx = 2 * (t & 3);
            v = ky * 40 + kx;
        } else {
            const int k = t + 32;
            if (k < 72) {
                const int p = k >> 1, lo = k & 1, ky = p >> 2, kx = 2 * (p & 3) + lo;
                v = ky * 40 + kx;
            } else if (k < 81) {
                v = (k - 72) * 40 + 8;
            } else v = 28;                       // uniform zero dword (broadcast)
        }
        offT[t] = (unsigned short)(4 * v);
    }
    if (t < 32) pbs[t] = prim_b[t];
    __syncthreads();

    // hoist per-lane tap byte-offsets
    unsigned tp0[4], tp1[4], t2a[4], t2b[4];
#pragma unroll
    for (int r = 0; r < 4; ++r) {
        tp0[r] = offT[quad * 4 + r];
        tp1[r] = offT[16 + quad * 4 + r];
        t2a[r] = offT[32 + quad * 8 + 2 * r];
        t2b[r] = offT[32 + quad * 8 + 2 * r + 1];
    }

    // ======== conv1: single d-slice, 25 mt tiles stride-4 across 4 waves ========
    {
        for (int mt = wave; mt < 25; mt += 4) {
            const int pos = mt * 16 + l16;
            const int y = (int)(((unsigned)pos * 52429u) >> 20);  // pos/20
            const unsigned pb4 = (unsigned)(pos + 20 * y) * 4u;   // 4*(y*40+x)
            f32x4 a0 = {0.f, 0.f, 0.f, 0.f}, a1 = {0.f, 0.f, 0.f, 0.f};
            union { unsigned u[4]; bf16x8 v; } A;
#pragma unroll
            for (int r = 0; r < 4; ++r)
                A.u[r] = *(const unsigned*)((const char*)imgp + (pb4 + tp0[r]));
            a0 = __builtin_amdgcn_mfma_f32_16x16x32_bf16(A.v, Bw0[0], a0, 0, 0, 0);
            a1 = __builtin_amdgcn_mfma_f32_16x16x32_bf16(A.v, Bw1[0], a1, 0, 0, 0);
#pragma unroll
            for (int r = 0; r < 4; ++r)
                A.u[r] = *(const unsigned*)((const char*)imgp + (pb4 + tp1[r]));
            a0 = __builtin_amdgcn_mfma_f32_16x16x32_bf16(A.v, Bw0[1], a0, 0, 0, 0);
            a1 = __builtin_amdgcn_mfma_f32_16x16x32_bf16(A.v, Bw1[1], a1, 0, 0, 0);
#pragma unroll
            for (int r = 0; r < 4; ++r) {
                const unsigned lo = *(const unsigned*)((const char*)imgp + (pb4 + t2a[r]));
                const unsigned hi = *(const unsigned*)((const char*)imgp + (pb4 + t2b[r]));
                A.u[r] = (lo & 0xFFFFu) | (hi << 16);
            }
            a0 = __builtin_amdgcn_mfma_f32_16x16x32_bf16(A.v, Bw0[2], a0, 0, 0, 0);
            a1 = __builtin_amdgcn_mfma_f32_16x16x32_bf16(A.v, Bw1[2], a1, 0, 0, 0);
            // packed b32 store: slot 2*l16 = caps l16 (a0), slot 2*l16+1 = caps 16+l16 (a1)
#pragma unroll
            for (int r = 0; r < 4; ++r) {
                const int pr = mt * 16 + quad * 4 + r;
                const int spar = (int)((((unsigned)pr * 52429u) >> 21) & 1u);
                const int base2 = pr * 40 + 8 * spar;
                const unsigned pk = (unsigned)f2bf(fmaxf(a0[r] + cb0, 0.f))
                                  | ((unsigned)f2bf(fmaxf(a1[r] + cb1, 0.f)) << 16);
                *(unsigned*)&c1t[base2 + 2 * l16] = pk;
            }
        }
    }
    __syncthreads();   // drains vmcnt(0): prologue taps 0-2 landed in abuf

    // ======== prim GEMM: per-tap loop, LDS A-FIFO depth 3, counted vmcnt ======
    const int hp = l16 >> 3, wp = l16 & 7;               // n = 8h' + w'
    const unsigned Lbase = 80u * (unsigned)(40 * hp + 2 * wp) + 16u * quad;
    const unsigned Lh0 = Lbase + 16u * hp;               // kk=0: spar=hp
    const unsigned Lh1 = Lbase + 16u * (1 - hp);         // kk=1: spar=1-hp

    f32x4 pa[6];
#pragma unroll
    for (int q = 0; q < 6; ++q) pa[q] = (f32x4){0.f, 0.f, 0.f, 0.f};

    for (int k = 0; k < ntap; ++k) {
        // issue tap k+3 into the buffer consumed at iteration k-1 (safe)
        const int nk = k + 3;
        if (nk < ntap) {
            const unsigned short* g = pw2 + (base + nk) * 1024 + lane * 8;
            unsigned short* l = &abuf[wave][nk & 3][0];
            gload16(g, l);
            gload16(g + 512, l + 512);
        }
        // tap k landed when <=6 loads outstanding (taps k+1..k+3 in flight)
        asm volatile("s_waitcnt vmcnt(6)" ::: "memory");

        const unsigned short* ab = &abuf[wave][k & 3][0];
        const bf16x8 Aa = *(const bf16x8*)(ab + l16 * 32 + quad * 8);
        const bf16x8 Ab = *(const bf16x8*)(ab + 512 + l16 * 32 + quad * 8);

        const int off = base + k;
        const int ky = (off * 57) >> 9;
        const int kx = off - 9 * ky;
        const int kk = (ky >> 1) & 1;
        const unsigned soff = 80u * (unsigned)(20 * ky + kx);
        const unsigned ad = (kk ? Lh1 : Lh0) + soff;
        const char* b0 = (const char*)c1t + ad;
#pragma unroll
        for (int nt = 0; nt < 3; ++nt) {
            const bf16x8 Bf = *(const bf16x8*)(b0 + nt * 6400);
            pa[nt]     = __builtin_amdgcn_mfma_f32_16x16x32_bf16(Aa, Bf, pa[nt],     0, 0, 0);
            pa[3 + nt] = __builtin_amdgcn_mfma_f32_16x16x32_bf16(Ab, Bf, pa[3 + nt], 0, 0, 0);
        }
    }
    __syncthreads();

    // ---- 4-wave tap reduction (redbuf overlays c1t), fold split by q ----
    f32x4* redbuf = (f32x4*)c1t;
#pragma unroll
    for (int q = 0; q < 6; ++q) redbuf[(wave * 6 + q) * 64 + lane] = pa[q];
    __syncthreads();

    float part[16];
#pragma unroll
    for (int k = 0; k < 16; ++k) part[k] = 0.f;

#define FOLDQ(QV)                                                           \
    {                                                                       \
        const int q = (QV);                                                 \
        f32x4 u4 = redbuf[q * 64 + lane];                                   \
        u4 += redbuf[(6 + q) * 64 + lane];                                  \
        u4 += redbuf[(12 + q) * 64 + lane];                                 \
        u4 += redbuf[(18 + q) * 64 + lane];                                 \
        if (wp < 6) {                                                       \
            const int mt = (q >= 3) ? 1 : 0;                                \
            const int nt = q - 3 * mt;                                      \
            const int h = 2 * nt + hp;                                      \
            _Pragma("unroll")                                               \
            for (int r = 0; r < 4; ++r) {                                   \
                const int o = mt * 16 + quad * 4 + r;                       \
                const float val = fmaxf(u4[r] + pbs[o], 0.f);               \
                const int nc = o * 36 + wp * 6 + h;                         \
                const f32x4* wd = (const f32x4*)&dig_W[(nc * 8 + d) * 16];  \
                _Pragma("unroll")                                           \
                for (int m = 0; m < 4; ++m) {                               \
                    const f32x4 wv = wd[m];                                 \
                    part[m * 4 + 0] = fmaf(val, wv[0], part[m * 4 + 0]);    \
                    part[m * 4 + 1] = fmaf(val, wv[1], part[m * 4 + 1]);    \
                    part[m * 4 + 2] = fmaf(val, wv[2], part[m * 4 + 2]);    \
                    part[m * 4 + 3] = fmaf(val, wv[3], part[m * 4 + 3]);    \
                }                                                           \
            }                                                               \
        }                                                                   \
    }

    // wave -> q assignment: w0:{0,4} w1:{1,5} w2:{2} w3:{3}
    FOLDQ(wave);
    if (wave < 2) FOLDQ(wave + 4);
#undef FOLDQ

    // ---- payload-splitting butterfly reduction: 16 k over 64 lanes ----
    float v8[8];
    {
        const bool hi5 = (lane & 32) != 0;
#pragma unroll
        for (int j = 0; j < 8; ++j) {
            const float keep = hi5 ? part[8 + j] : part[j];
            const float send = hi5 ? part[j] : part[8 + j];
            v8[j] = keep + __shfl_xor(send, 32, 64);
        }
    }
    float v4[4];
    {
        const bool hi4 = (lane & 16) != 0;
#pragma unroll
        for (int j = 0; j < 4; ++j) {
            const float keep = hi4 ? v8[4 + j] : v8[j];
            const float send = hi4 ? v8[j] : v8[4 + j];
            v4[j] = keep + __shfl_xor(send, 16, 64);
        }
    }
    float v2[2];
    {
        const bool hi3 = (lane & 8) != 0;
#pragma unroll
        for (int j = 0; j < 2; ++j) {
            const float keep = hi3 ? v4[2 + j] : v4[j];
            const float send = hi3 ? v4[j] : v4[2 + j];
            v2[j] = keep + __shfl_xor(send, 8, 64);
        }
    }
    float v1;
    {
        const bool hi2 = (lane & 4) != 0;
        const float keep = hi2 ? v2[1] : v2[0];
        const float send = hi2 ? v2[0] : v2[1];
        v1 = keep + __shfl_xor(send, 4, 64);
    }
    v1 += __shfl_xor(v1, 2, 64);
    v1 += __shfl_xor(v1, 1, 64);
    if ((lane & 3) == 0) sacc[wave * 16 + ((lane >> 2) & 15)] = v1;
    __syncthreads();
    if (t < 16) {
        const float v = sacc[t] + sacc[16 + t] + sacc[32 + t] + sacc[48 + t];
        atomicAdd(&S[b * 16 + t], v);
    }
    // __syncthreads drains vmcnt(0): S atomics complete before cnt RMW.
    __syncthreads();

    // ---- fused epilogue: 8th arriving block for image b finishes it ----
    if (t == 0) {
        const unsigned old = atomicAdd(&cnt[b], 1u);
        if (old == 7u) {
            float Sv[16]; float l2 = 0.f, l1 = 0.f;
#pragma unroll
            for (int k = 0; k < 16; ++k) {
                const float sv = (__hip_atomic_load(&S[b * 16 + k], __ATOMIC_RELAXED,
                                                    __HIP_MEMORY_SCOPE_AGENT)
                                  + colsum[k]) * (1.f / 1152.f);
                Sv[k] = sv; l2 += sv * sv; l1 += fabsf(sv);
            }
            l2 = sqrtf(l2);
            const float sc = l2 / (1.f + l2) / l1;
            float lg[10]; float mx = -1e30f;
#pragma unroll
            for (int o = 0; o < 10; ++o) {
                float a = out_b[o];
#pragma unroll
                for (int k = 0; k < 16; ++k) a = fmaf(Sv[k] * sc, OW[o * 16 + k], a);
                lg[o] = a; mx = fmaxf(mx, a);
            }
            float sum = 0.f;
#pragma unroll
            for (int o = 0; o < 10; ++o) { lg[o] = expf(lg[o] - mx); sum += lg[o]; }
            const float inv = 1.f / sum;
#pragma unroll
            for (int o = 0; o < 10; ++o) out[b * 10 + o] = lg[o] * inv;
        }
    }
}

extern "C" void kernel_launch(void* const* d_in, const int* in_sizes, int n_in,
                              void* d_out, int out_size, void* d_ws, size_t ws_size,
                              hipStream_t stream) {
    const float* x       = (const float*)d_in[0];
    const float* conv1_w = (const float*)d_in[1];
    const float* conv1_b = (const float*)d_in[2];
    const float* prim_w  = (const float*)d_in[3];
    const float* prim_b  = (const float*)d_in[4];
    const float* dig_W   = (const float*)d_in[5];
    const float* dig_Wb  = (const float*)d_in[6];
    const float* out_w   = (const float*)d_in[7];
    const float* out_b   = (const float*)d_in[8];
    float* out = (float*)d_out;

    const int B = in_sizes[0] / 784;   // 512

    char* w = (char*)d_ws;
    float* S              = (float*)(w);                             // 32768 B
    float* colsum         = (float*)(w + 32768);                     // 64 B
    float* OW             = (float*)(w + 32832);                     // 640 B
    unsigned short* c1wp2 = (unsigned short*)(w + 33472);            // 49152 B
    unsigned short* pw2   = (unsigned short*)(w + 33472 + 49152);    // 174080 B
    unsigned int* cnt     = (unsigned int*)(w + 256704);             // 2048 B

    const int zblocks = (B * 17 + 255) / 256;
    caps_pre<<<129 + zblocks, 256, 0, stream>>>(conv1_w, prim_w, dig_Wb, out_w,
                                                S, colsum, OW, c1wp2, pw2, cnt, B);
    caps_main<<<B * 8, 256, 0, stream>>>(x, conv1_b, prim_b, dig_W, c1wp2, pw2,
                                         S, colsum, OW, out_b, cnt, out);
}

// Round 17
// 167.671 us; speedup vs baseline: 1.2438x; 1.2438x over previous
//
#include <hip/hip_runtime.h>
#include <math.h>

// CapsNet fused forward, v20 = v18 verbatim (session best: 167.8us total,
// caps_main 109.4us). v19's LDS A-FIFO regressed (150.8us): 70KB LDS halved
// occupancy to 2 blocks/CU AND the A ds_read stride (64B = 16 banks) was an
// 8-way conflict (8.4M -> 11.0M). Reverting to the verified best.
// Final structure: 2 kernels; caps_main = one block per (image, d);
// hoisted prolog loads (prim group-0 + conv1 weights + biases) hide L2
// latency under vectorized float4 imgp staging; conv1 via 16x16x32 bf16
// MFMA with per-lane tap tables; prim GEMM 21 taps/wave with depth-2
// software prefetch (compiler sinks it, VGPR=64 — proven immovable);
// 4-wave LDS reduction + payload-splitting butterfly; fence-free fused
// epilogue (8th arriving block per image runs squash+dense+softmax).

typedef __attribute__((ext_vector_type(8))) short bf16x8;
typedef __attribute__((ext_vector_type(4))) float f32x4;

__device__ inline unsigned short f2bf(float f) {
    union { float f; unsigned u; } v; v.f = f;
    unsigned r = v.u + 0x7fff + ((v.u >> 16) & 1);   // RNE
    return (unsigned short)(r >> 16);
}

#define C1TN 16008   // u16 per c1t slice (400*40 + 8 skew pad)

// ---------------- pre kernel ----------------
__global__ void caps_pre(const float* __restrict__ conv1_w,
                         const float* __restrict__ prim_w,
                         const float* __restrict__ dig_Wb,
                         const float* __restrict__ out_w,
                         float* __restrict__ S,              // [B*16]
                         float* __restrict__ colsum,         // [16]
                         float* __restrict__ OW,             // [160]
                         unsigned short* __restrict__ c1wp2, // [256*96]
                         unsigned short* __restrict__ pw2,   // [85*1024]
                         unsigned int* __restrict__ cnt,     // [B]
                         int B)
{
    const int t = threadIdx.x;
    const int bx = blockIdx.x;

    if (bx < 32) {
        // pw2 build for o = bx: coalesced read + LDS transpose + coalesced write
        __shared__ float lw[2592];                  // [32 caps][81 taps]
        const float* src = prim_w + bx * 32 * 81;
        for (int j = t; j < 2592; j += 256) lw[j] = src[j];
        __syncthreads();
        unsigned short* dst = pw2 + bx * 32;
        for (int f = t; f < 2720; f += 256) {       // 85 taps * 32 slots
            const int tap = f >> 5, s = f & 31;
            const int ci = (s >> 1) + ((s & 1) << 4);   // interleaved caps slot
            const unsigned short v =
                (tap < 81) ? f2bf(lw[ci * 81 + tap]) : (unsigned short)0;
            dst[tap * 1024 + s] = v;
        }
        return;
    }
    if (bx < 128) {                                 // c1wp2, K-permuted
        const int tid = (bx - 32) * 256 + t;        // [0, 24576)
        const int c = tid / 96, kn = tid % 96;
        unsigned short v = 0;
        if (kn < 72) {
            const int p = kn >> 1, lo = kn & 1, ky = p >> 2, kx = 2 * (p & 3) + lo;
            v = f2bf(conv1_w[c * 81 + 9 * ky + kx]);
        } else if (kn < 81) {
            v = f2bf(conv1_w[c * 81 + 9 * (kn - 72) + 8]);
        }
        c1wp2[tid] = v;
        return;
    }
    if (bx == 128) {                                // colsum + OW
        __shared__ float cs[16];
        if (t < 16) cs[t] = 0.f;
        __syncthreads();
        {
            const int k = t & 15, g = t >> 4;
            float s = 0.f;
            for (int j = 0; j < 72; ++j) s += dig_Wb[(g * 72 + j) * 16 + k];
            atomicAdd(&cs[k], s);
        }
        __syncthreads();
        if (t < 16) colsum[t] = cs[t];
        if (t >= 64 && t < 224) {
            const int idx = t - 64, o = idx >> 4, k = idx & 15;
            float s = 0.f;
            for (int i = 0; i < 10; ++i) s += out_w[(o * 10 + i) * 16 + k];
            OW[idx] = s;
        }
        return;
    }
    const int idx = (bx - 129) * 256 + t;           // S / cnt zero
    if (idx < B * 16) S[idx] = 0.f;
    else if (idx < B * 17) cnt[idx - B * 16] = 0u;
}

// ---------------- main kernel (epilogue fused, fence-free) ----------------
__global__ __launch_bounds__(256, 3) void caps_main(
    const float* __restrict__ x,
    const float* __restrict__ conv1_b,
    const float* __restrict__ prim_b,
    const float* __restrict__ dig_W,
    const unsigned short* __restrict__ c1wp2,
    const unsigned short* __restrict__ pw2,
    float* __restrict__ S,
    const float* __restrict__ colsum,
    const float* __restrict__ OW,
    const float* __restrict__ out_b,
    unsigned int* __restrict__ cnt,
    float* __restrict__ out)
{
    __shared__ __align__(16) unsigned short c1t[C1TN];      // 32 KB (1 d-slice)
    __shared__ __align__(16) unsigned imgp[1120];           // 28x40-dw bf16-pair grid
    __shared__ unsigned short offT[64];                     // byte offsets into imgp
    __shared__ float pbs[32];
    __shared__ float sacc[64];                              // per-wave S partials

    const int b = blockIdx.x >> 3, d = blockIdx.x & 7;
    const int t = threadIdx.x;
    const int wave = t >> 6, lane = t & 63, quad = lane >> 4, l16 = lane & 15;

    // ---- prim tap partition: 21 contiguous taps per wave (w3: 18 real) ----
    const int base = wave * 21;                 // 0,21,42,63

    // ---- hoisted prolog loads: prim group 0 + conv1 weight frags + biases ----
    const unsigned short* apbase = pw2 + l16 * 32 + quad * 8;
    bf16x8 A0a = *(const bf16x8*)(apbase + (base + 0) * 1024);
    bf16x8 A0b = *(const bf16x8*)(apbase + (base + 0) * 1024 + 512);
    bf16x8 A1a = *(const bf16x8*)(apbase + (base + 1) * 1024);
    bf16x8 A1b = *(const bf16x8*)(apbase + (base + 1) * 1024 + 512);
    bf16x8 A2a = *(const bf16x8*)(apbase + (base + 2) * 1024);
    bf16x8 A2b = *(const bf16x8*)(apbase + (base + 2) * 1024 + 512);
    bf16x8 Bw0[3], Bw1[3];
#pragma unroll
    for (int ks = 0; ks < 3; ++ks) {
        Bw0[ks] = *(const bf16x8*)&c1wp2[(l16 * 8 + d) * 96 + ks * 32 + quad * 8];
        Bw1[ks] = *(const bf16x8*)&c1wp2[((16 + l16) * 8 + d) * 96 + ks * 32 + quad * 8];
    }
    const float cb0 = conv1_b[l16 * 8 + d];
    const float cb1 = conv1_b[(16 + l16) * 8 + d];
    __builtin_amdgcn_sched_barrier(0);          // loads may not sink past here

    // ---- imgp staging, vectorized, 28x40-dw grid ----
    const float* xb = x + b * 784;
    if (t < 196) {
        const float4 f4 = *(const float4*)(xb + 4 * t);
        const float nxt = (t < 195) ? xb[4 * t + 4] : 0.f;
        const float e[5] = {f4.x, f4.y, f4.z, f4.w, nxt};
#pragma unroll
        for (int r = 0; r < 4; ++r) {
            const int j = 4 * t + r;
            const int y = (int)(((unsigned)j * 37450u) >> 20);   // j/28
            const int xc = j - 28 * y;
            const float cnext = (xc < 27) ? e[r + 1] : 0.f;
            imgp[y * 40 + xc] = (unsigned)f2bf(e[r]) | ((unsigned)f2bf(cnext) << 16);
        }
    }
    // zero-fill cols 28..39 (includes the uniform dead-tap dword at index 28)
    for (int j = t; j < 1120; j += 256) {
        const int y = (int)(((unsigned)j * 1639u) >> 16);        // j/40
        if (j - 40 * y >= 28) imgp[j] = 0u;
    }
    // ---- tap-offset tables (byte offsets, x4), stride-40 grid ----
    if (t < 64) {
        int v;
        if (t < 32) {
            const int ky = t >> 2, kx = 2 * (t & 3);
            v = ky * 40 + kx;
        } else {
            const int k = t + 32;
            if (k < 72) {
                const int p = k >> 1, lo = k & 1, ky = p >> 2, kx = 2 * (p & 3) + lo;
                v = ky * 40 + kx;
            } else if (k < 81) {
                v = (k - 72) * 40 + 8;
            } else v = 28;                       // uniform zero dword (broadcast)
        }
        offT[t] = (unsigned short)(4 * v);
    }
    if (t < 32) pbs[t] = prim_b[t];
    __syncthreads();

    // hoist per-lane tap byte-offsets
    unsigned tp0[4], tp1[4], t2a[4], t2b[4];
#pragma unroll
    for (int r = 0; r < 4; ++r) {
        tp0[r] = offT[quad * 4 + r];
        tp1[r] = offT[16 + quad * 4 + r];
        t2a[r] = offT[32 + quad * 8 + 2 * r];
        t2b[r] = offT[32 + quad * 8 + 2 * r + 1];
    }

    // ======== conv1: single d-slice, 25 mt tiles stride-4 across 4 waves ========
    {
        for (int mt = wave; mt < 25; mt += 4) {
            const int pos = mt * 16 + l16;
            const int y = (int)(((unsigned)pos * 52429u) >> 20);  // pos/20
            const unsigned pb4 = (unsigned)(pos + 20 * y) * 4u;   // 4*(y*40+x)
            f32x4 a0 = {0.f, 0.f, 0.f, 0.f}, a1 = {0.f, 0.f, 0.f, 0.f};
            union { unsigned u[4]; bf16x8 v; } A;
#pragma unroll
            for (int r = 0; r < 4; ++r)
                A.u[r] = *(const unsigned*)((const char*)imgp + (pb4 + tp0[r]));
            a0 = __builtin_amdgcn_mfma_f32_16x16x32_bf16(A.v, Bw0[0], a0, 0, 0, 0);
            a1 = __builtin_amdgcn_mfma_f32_16x16x32_bf16(A.v, Bw1[0], a1, 0, 0, 0);
#pragma unroll
            for (int r = 0; r < 4; ++r)
                A.u[r] = *(const unsigned*)((const char*)imgp + (pb4 + tp1[r]));
            a0 = __builtin_amdgcn_mfma_f32_16x16x32_bf16(A.v, Bw0[1], a0, 0, 0, 0);
            a1 = __builtin_amdgcn_mfma_f32_16x16x32_bf16(A.v, Bw1[1], a1, 0, 0, 0);
#pragma unroll
            for (int r = 0; r < 4; ++r) {
                const unsigned lo = *(const unsigned*)((const char*)imgp + (pb4 + t2a[r]));
                const unsigned hi = *(const unsigned*)((const char*)imgp + (pb4 + t2b[r]));
                A.u[r] = (lo & 0xFFFFu) | (hi << 16);
            }
            a0 = __builtin_amdgcn_mfma_f32_16x16x32_bf16(A.v, Bw0[2], a0, 0, 0, 0);
            a1 = __builtin_amdgcn_mfma_f32_16x16x32_bf16(A.v, Bw1[2], a1, 0, 0, 0);
            // packed b32 store: slot 2*l16 = caps l16 (a0), slot 2*l16+1 = caps 16+l16 (a1)
#pragma unroll
            for (int r = 0; r < 4; ++r) {
                const int pr = mt * 16 + quad * 4 + r;
                const int spar = (int)((((unsigned)pr * 52429u) >> 21) & 1u);
                const int base2 = pr * 40 + 8 * spar;
                const unsigned pk = (unsigned)f2bf(fmaxf(a0[r] + cb0, 0.f))
                                  | ((unsigned)f2bf(fmaxf(a1[r] + cb1, 0.f)) << 16);
                *(unsigned*)&c1t[base2 + 2 * l16] = pk;
            }
        }
    }
    __syncthreads();

    // ======== prim GEMM: groups of 3, depth-2 prefetch; w3 skips zero group ===
    const int hp = l16 >> 3, wp = l16 & 7;               // n = 8h' + w'
    const unsigned Lbase = 80u * (unsigned)(40 * hp + 2 * wp) + 16u * quad;
    const unsigned Lh0 = Lbase + 16u * hp;               // kk=0: spar=hp
    const unsigned Lh1 = Lbase + 16u * (1 - hp);         // kk=1: spar=1-hp

    f32x4 pa[6];
#pragma unroll
    for (int q = 0; q < 6; ++q) pa[q] = (f32x4){0.f, 0.f, 0.f, 0.f};

    // issue group 1 (pending)
    bf16x8 P0a = *(const bf16x8*)(apbase + (base + 3) * 1024);
    bf16x8 P0b = *(const bf16x8*)(apbase + (base + 3) * 1024 + 512);
    bf16x8 P1a = *(const bf16x8*)(apbase + (base + 4) * 1024);
    bf16x8 P1b = *(const bf16x8*)(apbase + (base + 4) * 1024 + 512);
    bf16x8 P2a = *(const bf16x8*)(apbase + (base + 5) * 1024);
    bf16x8 P2b = *(const bf16x8*)(apbase + (base + 5) * 1024 + 512);
    __builtin_amdgcn_sched_barrier(0);

#pragma unroll
    for (int g = 0; g < 7; ++g) {
        // wave 3's group 6 = taps 81-83 (zero-padded): skip entirely
        if (g < 6 || wave != 3) {
            // issue group g+2 (clamped: over-prefetched groups never consumed;
            // taps 81..84 exist and are zero-padded)
            int nb = base + 3 * g + 6;
            nb = (nb > 82) ? 82 : nb;
            const bf16x8 N0a = *(const bf16x8*)(apbase + (nb + 0) * 1024);
            const bf16x8 N0b = *(const bf16x8*)(apbase + (nb + 0) * 1024 + 512);
            const bf16x8 N1a = *(const bf16x8*)(apbase + (nb + 1) * 1024);
            const bf16x8 N1b = *(const bf16x8*)(apbase + (nb + 1) * 1024 + 512);
            const bf16x8 N2a = *(const bf16x8*)(apbase + (nb + 2) * 1024);
            const bf16x8 N2b = *(const bf16x8*)(apbase + (nb + 2) * 1024 + 512);
            __builtin_amdgcn_sched_barrier(0);   // loads stay issued above MFMAs

#pragma unroll
            for (int j = 0; j < 3; ++j) {
                const int off = base + 3 * g + j;    // <= 80 real taps here
                const int ky = (off * 57) >> 9;
                const int kx = off - 9 * ky;
                const int kk = (ky >> 1) & 1;
                const unsigned soff = 80u * (unsigned)(20 * ky + kx);
                const unsigned ad = (kk ? Lh1 : Lh0) + soff;
                const char* b0 = (const char*)c1t + ad;
                const bf16x8 Aa = (j == 0) ? A0a : (j == 1) ? A1a : A2a;
                const bf16x8 Ab = (j == 0) ? A0b : (j == 1) ? A1b : A2b;
#pragma unroll
                for (int nt = 0; nt < 3; ++nt) {
                    const bf16x8 Bf = *(const bf16x8*)(b0 + nt * 6400);
                    pa[nt]     = __builtin_amdgcn_mfma_f32_16x16x32_bf16(Aa, Bf, pa[nt],     0, 0, 0);
                    pa[3 + nt] = __builtin_amdgcn_mfma_f32_16x16x32_bf16(Ab, Bf, pa[3 + nt], 0, 0, 0);
                }
            }
            // rotate FIFO (renamed by full unroll, no v_mov cost)
            A0a = P0a; A0b = P0b; A1a = P1a; A1b = P1b; A2a = P2a; A2b = P2b;
            P0a = N0a; P0b = N0b; P1a = N1a; P1b = N1b; P2a = N2a; P2b = N2b;
        }
    }
    __syncthreads();

    // ---- 4-wave tap reduction (redbuf overlays c1t), fold split by q ----
    f32x4* redbuf = (f32x4*)c1t;
#pragma unroll
    for (int q = 0; q < 6; ++q) redbuf[(wave * 6 + q) * 64 + lane] = pa[q];
    __syncthreads();

    float part[16];
#pragma unroll
    for (int k = 0; k < 16; ++k) part[k] = 0.f;

#define FOLDQ(QV)                                                           \
    {                                                                       \
        const int q = (QV);                                                 \
        f32x4 u4 = redbuf[q * 64 + lane];                                   \
        u4 += redbuf[(6 + q) * 64 + lane];                                  \
        u4 += redbuf[(12 + q) * 64 + lane];                                 \
        u4 += redbuf[(18 + q) * 64 + lane];                                 \
        if (wp < 6) {                                                       \
            const int mt = (q >= 3) ? 1 : 0;                                \
            const int nt = q - 3 * mt;                                      \
            const int h = 2 * nt + hp;                                      \
            _Pragma("unroll")                                               \
            for (int r = 0; r < 4; ++r) {                                   \
                const int o = mt * 16 + quad * 4 + r;                       \
                const float val = fmaxf(u4[r] + pbs[o], 0.f);               \
                const int nc = o * 36 + wp * 6 + h;                         \
                const f32x4* wd = (const f32x4*)&dig_W[(nc * 8 + d) * 16];  \
                _Pragma("unroll")                                           \
                for (int m = 0; m < 4; ++m) {                               \
                    const f32x4 wv = wd[m];                                 \
                    part[m * 4 + 0] = fmaf(val, wv[0], part[m * 4 + 0]);    \
                    part[m * 4 + 1] = fmaf(val, wv[1], part[m * 4 + 1]);    \
                    part[m * 4 + 2] = fmaf(val, wv[2], part[m * 4 + 2]);    \
                    part[m * 4 + 3] = fmaf(val, wv[3], part[m * 4 + 3]);    \
                }                                                           \
            }                                                               \
        }                                                                   \
    }

    // wave -> q assignment: w0:{0,4} w1:{1,5} w2:{2} w3:{3}
    FOLDQ(wave);
    if (wave < 2) FOLDQ(wave + 4);
#undef FOLDQ

    // ---- payload-splitting butterfly reduction: 16 k over 64 lanes ----
    float v8[8];
    {
        const bool hi5 = (lane & 32) != 0;
#pragma unroll
        for (int j = 0; j < 8; ++j) {
            const float keep = hi5 ? part[8 + j] : part[j];
            const float send = hi5 ? part[j] : part[8 + j];
            v8[j] = keep + __shfl_xor(send, 32, 64);
        }
    }
    float v4[4];
    {
        const bool hi4 = (lane & 16) != 0;
#pragma unroll
        for (int j = 0; j < 4; ++j) {
            const float keep = hi4 ? v8[4 + j] : v8[j];
            const float send = hi4 ? v8[j] : v8[4 + j];
            v4[j] = keep + __shfl_xor(send, 16, 64);
        }
    }
    float v2[2];
    {
        const bool hi3 = (lane & 8) != 0;
#pragma unroll
        for (int j = 0; j < 2; ++j) {
            const float keep = hi3 ? v4[2 + j] : v4[j];
            const float send = hi3 ? v4[j] : v4[2 + j];
            v2[j] = keep + __shfl_xor(send, 8, 64);
        }
    }
    float v1;
    {
        const bool hi2 = (lane & 4) != 0;
        const float keep = hi2 ? v2[1] : v2[0];
        const float send = hi2 ? v2[0] : v2[1];
        v1 = keep + __shfl_xor(send, 4, 64);
    }
    v1 += __shfl_xor(v1, 2, 64);
    v1 += __shfl_xor(v1, 1, 64);
    if ((lane & 3) == 0) sacc[wave * 16 + ((lane >> 2) & 15)] = v1;
    __syncthreads();
    if (t < 16) {
        const float v = sacc[t] + sacc[16 + t] + sacc[32 + t] + sacc[48 + t];
        atomicAdd(&S[b * 16 + t], v);
    }
    // __syncthreads drains vmcnt(0): S atomics complete before cnt RMW.
    __syncthreads();

    // ---- fused epilogue: 8th arriving block for image b finishes it ----
    if (t == 0) {
        const unsigned old = atomicAdd(&cnt[b], 1u);
        if (old == 7u) {
            float Sv[16]; float l2 = 0.f, l1 = 0.f;
#pragma unroll
            for (int k = 0; k < 16; ++k) {
                const float sv = (__hip_atomic_load(&S[b * 16 + k], __ATOMIC_RELAXED,
                                                    __HIP_MEMORY_SCOPE_AGENT)
                                  + colsum[k]) * (1.f / 1152.f);
                Sv[k] = sv; l2 += sv * sv; l1 += fabsf(sv);
            }
            l2 = sqrtf(l2);
            const float sc = l2 / (1.f + l2) / l1;
            float lg[10]; float mx = -1e30f;
#pragma unroll
            for (int o = 0; o < 10; ++o) {
                float a = out_b[o];
#pragma unroll
                for (int k = 0; k < 16; ++k) a = fmaf(Sv[k] * sc, OW[o * 16 + k], a);
                lg[o] = a; mx = fmaxf(mx, a);
            }
            float sum = 0.f;
#pragma unroll
            for (int o = 0; o < 10; ++o) { lg[o] = expf(lg[o] - mx); sum += lg[o]; }
            const float inv = 1.f / sum;
#pragma unroll
            for (int o = 0; o < 10; ++o) out[b * 10 + o] = lg[o] * inv;
        }
    }
}

extern "C" void kernel_launch(void* const* d_in, const int* in_sizes, int n_in,
                              void* d_out, int out_size, void* d_ws, size_t ws_size,
                              hipStream_t stream) {
    const float* x       = (const float*)d_in[0];
    const float* conv1_w = (const float*)d_in[1];
    const float* conv1_b = (const float*)d_in[2];
    const float* prim_w  = (const float*)d_in[3];
    const float* prim_b  = (const float*)d_in[4];
    const float* dig_W   = (const float*)d_in[5];
    const float* dig_Wb  = (const float*)d_in[6];
    const float* out_w   = (const float*)d_in[7];
    const float* out_b   = (const float*)d_in[8];
    float* out = (float*)d_out;

    const int B = in_sizes[0] / 784;   // 512

    char* w = (char*)d_ws;
    float* S              = (float*)(w);                             // 32768 B
    float* colsum         = (float*)(w + 32768);                     // 64 B
    float* OW             = (float*)(w + 32832);                     // 640 B
    unsigned short* c1wp2 = (unsigned short*)(w + 33472);            // 49152 B
    unsigned short* pw2   = (unsigned short*)(w + 33472 + 49152);    // 174080 B
    unsigned int* cnt     = (unsigned int*)(w + 256704);             // 2048 B

    const int zblocks = (B * 17 + 255) / 256;
    caps_pre<<<129 + zblocks, 256, 0, stream>>>(conv1_w, prim_w, dig_Wb, out_w,
                                                S, colsum, OW, c1wp2, pw2, cnt, B);
    caps_main<<<B * 8, 256, 0, stream>>>(x, conv1_b, prim_b, dig_W, c1wp2, pw2,
                                         S, colsum, OW, out_b, cnt, out);
}